// Round 11
// baseline (1250.977 us; speedup 1.0000x reference)
//
#include <hip/hip_runtime.h>
#include <hip/hip_fp16.h>
#include <hip/hip_cooperative_groups.h>
#include <math.h>

namespace cg = cooperative_groups;

constexpr int NN = 50000;
constexpr int NE = 800000;
constexpr int NEP = NE + NN;            // edges + self-loops
constexpr int CAP = 96;                 // bucket capacity (Poisson(17), P(deg>96)~0)
constexpr int NT  = (NN + 63) / 64;     // 782 row tiles
constexpr int NQ  = NN / 4;             // 12500 node quads
constexpr int PACK_TOTAL = 7168;

typedef _Float16 half8_t __attribute__((ext_vector_type(8)));
typedef float    f32x4_t __attribute__((ext_vector_type(4)));

__device__ __forceinline__ float lrelu02(float x) { return x > 0.f ? x : 0.2f * x; }
__device__ __forceinline__ float eluf(float x)    { return x > 0.f ? x : (__expf(x) - 1.f); }
__device__ __forceinline__ float pick4(float4 q, int hd) {
  return (hd == 0) ? q.x : (hd == 1) ? q.y : (hd == 2) ? q.z : q.w;
}

// ---------------- W pre-pack into MFMA B-fragment order ----------------

__device__ __forceinline__ void pack_w_one(const float* __restrict__ W,
                                           __half* __restrict__ Wp,
                                           int M, int tid, int total) {
  if (tid >= total) return;
  int CT = M >> 4;
  int l = tid & 63;
  int c = (tid >> 6) % CT;
  int kc = (tid >> 6) / CT;
  int n = l & 15, q = l >> 4;
  __half* dst = Wp + (size_t)tid * 8;
  const float* src = W + (size_t)(kc * 32 + q * 8) * M + c * 16 + n;
  #pragma unroll
  for (int j = 0; j < 8; j++) dst[j] = __float2half_rn(src[j * M]);
}

// ---------------- phase: zero counts ----------------

__device__ __forceinline__ void zero_phase(int* __restrict__ count) {
  for (int i = blockIdx.x * 256 + threadIdx.x; i < NN; i += gridDim.x * 256)
    count[i] = 0;
}

// ---------------- phase: bucket scatter + weight pack ----------------

__device__ __forceinline__ void scatter_pack_phase(
    const int* __restrict__ edge_src, const int* __restrict__ edge_dst,
    int* __restrict__ count, int* __restrict__ csr_src,
    const float* W1, __half* Wp1, const float* W2, __half* Wp2,
    const float* W3, __half* Wp3, const float* W4, __half* Wp4,
    const float* Wr, __half* Wrp, const float* Wf1, __half* Wf1p) {
  for (int i = blockIdx.x * 256 + threadIdx.x; i < NEP + PACK_TOTAL; i += gridDim.x * 256) {
    if (i < NEP) {
      int s, d;
      if (i < NE) { s = edge_src[i]; d = edge_dst[i]; } else { s = i - NE; d = s; }
      int pos = atomicAdd(&count[d], 1);
      if (pos < CAP) csr_src[d * CAP + pos] = s;
    } else {
      int tid = i - NEP;
      if (tid < 512)            pack_w_one(W1, Wp1, 32,  tid,        512);
      else if (tid < 768)       pack_w_one(W2, Wp2, 64,  tid - 512,  256);
      else if (tid < 1792)      pack_w_one(W3, Wp3, 128, tid - 768,  1024);
      else if (tid < 5888)      pack_w_one(W4, Wp4, 256, tid - 1792, 4096);
      else if (tid < 6912)      pack_w_one(Wr, Wrp, 32,  tid - 5888, 1024);
      else                      pack_w_one(Wf1, Wf1p, 64, tid - 6912, 256);
    }
  }
}

// ---------------- phase: MFMA GEMM + fused alpha (chunked columns) ----------
// CHUNK<=8 accumulator fragments live at once (VGPR control); M=256 runs 2
// chunk passes re-staging A (cheap). Grid-stride over row tiles.

template<int M, int K, int C, bool F32A>
__device__ __forceinline__ void gemm_phase(const void* Av, const __half* __restrict__ Wp,
    __half* __restrict__ Ch, const float* __restrict__ a_src, const float* __restrict__ a_dst,
    float* __restrict__ as_out, float* __restrict__ ad_out, _Float16* Ah) {
  constexpr int CT = M / 16;
  constexpr int CHUNK = (CT > 8) ? 8 : CT;
  constexpr int NCH = CT / CHUNK;
  constexpr int KC = K / 32;
  int t = threadIdx.x;
  int w = t >> 6, l = t & 63, m = l & 15, q = l >> 4;
  const half8_t* Bfrag = (const half8_t*)Wp;

  for (int tile = blockIdx.x; tile < NT; tile += gridDim.x) {
    int row0 = tile * 64;
    #pragma unroll
    for (int ch = 0; ch < NCH; ch++) {
      f32x4_t acc[CHUNK];
      #pragma unroll
      for (int c = 0; c < CHUNK; c++) acc[c] = (f32x4_t){0.f, 0.f, 0.f, 0.f};
      for (int kc = 0; kc < KC; kc++) {
        __syncthreads();
        if constexpr (F32A) {
          const float* A = (const float*)Av;
          #pragma unroll
          for (int i = 0; i < 2; i++) {
            int idx = t + 256 * i;
            int row = idx >> 3, c4 = idx & 7;
            int gr = row0 + row; if (gr >= NN) gr = NN - 1;
            float4 vv = *(const float4*)(A + (size_t)gr * K + kc * 32 + c4 * 4);
            _Float16 h4[4] = {(_Float16)vv.x, (_Float16)vv.y, (_Float16)vv.z, (_Float16)vv.w};
            *(uint2*)(&Ah[row * 40 + c4 * 4]) = *(const uint2*)h4;
          }
        } else {
          const __half* A = (const __half*)Av;
          int row = t >> 2, c8 = t & 3;
          int gr = row0 + row; if (gr >= NN) gr = NN - 1;
          uint4 vv = *(const uint4*)(A + (size_t)gr * K + kc * 32 + c8 * 8);
          *(uint4*)(&Ah[row * 40 + c8 * 8]) = vv;
        }
        __syncthreads();
        half8_t a = *(const half8_t*)(&Ah[(w * 16 + m) * 40 + q * 8]);
        #pragma unroll
        for (int c = 0; c < CHUNK; c++) {
          half8_t b = Bfrag[(kc * CT + ch * CHUNK + c) * 64 + l];
          acc[c] = __builtin_amdgcn_mfma_f32_16x16x32_f16(a, b, acc[c], 0, 0, 0);
        }
      }
      int rbase = row0 + w * 16 + q * 4;
      #pragma unroll
      for (int r = 0; r < 4; r++) {
        int row = rbase + r;
        if (row < NN) {
          #pragma unroll
          for (int c = 0; c < CHUNK; c++)
            Ch[(size_t)row * M + (ch * CHUNK + c) * 16 + m] = __float2half_rn(acc[c][r]);
        }
      }
      // fused alpha for this chunk's columns
      float aS[CHUNK], aD[CHUNK];
      #pragma unroll
      for (int c = 0; c < CHUNK; c++) {
        int cg_ = ch * CHUNK + c;
        aS[c] = a_src[cg_ * 16 + m];
        aD[c] = a_dst[cg_ * 16 + m];
      }
      if constexpr (C == 8) {
        #pragma unroll
        for (int r = 0; r < 4; r++) {
          float p0 = acc[0][r] * aS[0], p1 = acc[1][r] * aS[1];
          float q0 = acc[0][r] * aD[0], q1 = acc[1][r] * aD[1];
          #pragma unroll
          for (int off = 1; off < 8; off <<= 1) {
            p0 += __shfl_xor(p0, off); p1 += __shfl_xor(p1, off);
            q0 += __shfl_xor(q0, off); q1 += __shfl_xor(q1, off);
          }
          int row = rbase + r;
          if ((m & 7) == 0 && row < NN) {
            int hb = m >> 3;
            as_out[row * 4 + hb]     = p0;
            as_out[row * 4 + 2 + hb] = p1;
            ad_out[row * 4 + hb]     = q0;
            ad_out[row * 4 + 2 + hb] = q1;
          }
        }
      } else {
        constexpr int FPH = C / 16;          // fragments per head
        constexpr int HPC = CHUNK / FPH;     // heads per chunk
        int headBase = ch * HPC;
        #pragma unroll
        for (int r = 0; r < 4; r++) {
          float bs[HPC], bd[HPC];
          #pragma unroll
          for (int hh = 0; hh < HPC; hh++) { bs[hh] = 0.f; bd[hh] = 0.f; }
          #pragma unroll
          for (int c = 0; c < CHUNK; c++) {
            int hh = c / FPH;
            bs[hh] += acc[c][r] * aS[c];
            bd[hh] += acc[c][r] * aD[c];
          }
          #pragma unroll
          for (int off = 1; off < 16; off <<= 1)
            #pragma unroll
            for (int hh = 0; hh < HPC; hh++) {
              bs[hh] += __shfl_xor(bs[hh], off);
              bd[hh] += __shfl_xor(bd[hh], off);
            }
          int row = rbase + r;
          if (m < HPC && row < NN) {
            float vs = bs[0], vd = bd[0];
            #pragma unroll
            for (int hh = 1; hh < HPC; hh++) if (m == hh) { vs = bs[hh]; vd = bd[hh]; }
            as_out[row * 4 + headBase + m] = vs;
            ad_out[row * 4 + headBase + m] = vd;
          }
        }
      }
    }
  }
}

// ---------------- phase: aggregation (wave-per-node, bucket CSR) ----------

template<int HC, int C>
__device__ __forceinline__ void agg_phase(const __half* __restrict__ h,
    const float* __restrict__ as_v, const float* __restrict__ ad_v,
    const int* __restrict__ count, const int* __restrict__ csr_src,
    const float* __restrict__ bias, __half* __restrict__ out,
    float4 (*see4)[CAP], int (*ssrc)[CAP]) {
  constexpr int V = HC / 8;
  constexpr int G = 64 / V;
  constexpr int P = 4;
  int wid = threadIdx.x >> 6, lane = threadIdx.x & 63;
  int g = lane / V, v = lane % V;
  int hd = (v * 8) / C;
  const float4* hrows = (const float4*)h;

  for (int qd = blockIdx.x; qd < NQ; qd += gridDim.x) {
    int dst = qd * 4 + wid;
    int base = dst * CAP;
    int deg = count[dst]; if (deg > CAP) deg = CAP;   // >= 1 (self-loop)
    float4 ad = *(const float4*)(ad_v + dst * 4);

    float d0 = 0.f, d1 = 0.f, d2 = 0.f, d3 = 0.f;
    #pragma unroll
    for (int it = 0; it < 2; it++) {
      int j = lane + it * 64;
      if (j < deg) {
        int s = csr_src[base + j];
        float4 as = *(const float4*)(as_v + s * 4);
        float4 x = make_float4(__expf(lrelu02(as.x + ad.x)), __expf(lrelu02(as.y + ad.y)),
                               __expf(lrelu02(as.z + ad.z)), __expf(lrelu02(as.w + ad.w)));
        ssrc[wid][j] = s; see4[wid][j] = x;
        d0 += x.x; d1 += x.y; d2 += x.z; d3 += x.w;
      }
    }
    #pragma unroll
    for (int off = 32; off > 0; off >>= 1) {
      d0 += __shfl_xor(d0, off); d1 += __shfl_xor(d1, off);
      d2 += __shfl_xor(d2, off); d3 += __shfl_xor(d3, off);
    }
    float4 inv4 = make_float4(1.f / d0, 1.f / d1, 1.f / d2, 1.f / d3);
    float invh = pick4(inv4, hd);

    float  px[P];
    float4 hv[P];
    #pragma unroll
    for (int k = 0; k < P; k++) {
      int jj = k * G + g;
      bool ok = jj < deg;
      int jc = ok ? jj : 0;
      int s = ssrc[wid][jc];
      float x = ((const float*)&see4[wid][jc])[hd];
      px[k] = ok ? x * invh : 0.f;
      hv[k] = hrows[(size_t)s * V + v];
    }
    float acc[8];
    #pragma unroll
    for (int i = 0; i < 8; i++) acc[i] = 0.f;
    int steps = (deg + G - 1) / G;
    int nB = (steps + P - 1) / P;
    for (int b = 1; b <= nB; b++) {
      #pragma unroll
      for (int k = 0; k < P; k++) {
        const __half2* hp = (const __half2*)&hv[k];
        float2 f0 = __half22float2(hp[0]);
        float2 f1 = __half22float2(hp[1]);
        float2 f2 = __half22float2(hp[2]);
        float2 f3 = __half22float2(hp[3]);
        float p = px[k];
        acc[0] += p * f0.x; acc[1] += p * f0.y;
        acc[2] += p * f1.x; acc[3] += p * f1.y;
        acc[4] += p * f2.x; acc[5] += p * f2.y;
        acc[6] += p * f3.x; acc[7] += p * f3.y;
        int jj = (b * P + k) * G + g;
        bool ok = jj < deg;
        int jc = ok ? jj : 0;
        int s = ssrc[wid][jc];
        float x = ((const float*)&see4[wid][jc])[hd];
        px[k] = ok ? x * invh : 0.f;
        hv[k] = hrows[(size_t)s * V + v];
      }
    }
    #pragma unroll
    for (int off = V; off < 64; off <<= 1)
      #pragma unroll
      for (int i = 0; i < 8; i++) acc[i] += __shfl_xor(acc[i], off);

    if (lane < V) {
      const float4* b4p = (const float4*)bias;
      float4 ba = b4p[2 * v], bb = b4p[2 * v + 1];
      _Float16 o[8];
      o[0] = (_Float16)eluf(acc[0] + ba.x); o[1] = (_Float16)eluf(acc[1] + ba.y);
      o[2] = (_Float16)eluf(acc[2] + ba.z); o[3] = (_Float16)eluf(acc[3] + ba.w);
      o[4] = (_Float16)eluf(acc[4] + bb.x); o[5] = (_Float16)eluf(acc[5] + bb.y);
      o[6] = (_Float16)eluf(acc[6] + bb.z); o[7] = (_Float16)eluf(acc[7] + bb.w);
      *(uint4*)(out + (size_t)dst * HC + v * 8) = *(const uint4*)o;
    }
  }
}

// ---------------- phase: MFMA MLP head 256 -> 32 -> 64 -> 1 ----------------

__device__ __forceinline__ void mlp_phase(const __half* __restrict__ h4,
    const __half* __restrict__ Wrp, const float* __restrict__ br,
    const __half* __restrict__ Wf1p, const float* __restrict__ bf1,
    const float* __restrict__ Wf2, const float* __restrict__ bf2,
    float* __restrict__ out, _Float16* rS) {
  int t = threadIdx.x;
  int wid = t >> 6, l = t & 63, m = l & 15, q = l >> 4;
  const half8_t* Bwr  = (const half8_t*)Wrp;
  const half8_t* Bwf1 = (const half8_t*)Wf1p;

  for (int tile = blockIdx.x; tile < NT; tile += gridDim.x) {
    int row0 = tile * 64;
    int arow = row0 + wid * 16 + m; if (arow >= NN) arow = NN - 1;
    const half8_t* Arow = (const half8_t*)(h4 + (size_t)arow * 256);
    half8_t afr[8];
    #pragma unroll
    for (int kc = 0; kc < 8; kc++) afr[kc] = Arow[kc * 4 + q];
    f32x4_t acc1[2];
    acc1[0] = (f32x4_t){0.f, 0.f, 0.f, 0.f};
    acc1[1] = (f32x4_t){0.f, 0.f, 0.f, 0.f};
    #pragma unroll
    for (int kc = 0; kc < 8; kc++) {
      acc1[0] = __builtin_amdgcn_mfma_f32_16x16x32_f16(afr[kc], Bwr[(kc * 2 + 0) * 64 + l], acc1[0], 0, 0, 0);
      acc1[1] = __builtin_amdgcn_mfma_f32_16x16x32_f16(afr[kc], Bwr[(kc * 2 + 1) * 64 + l], acc1[1], 0, 0, 0);
    }
    __syncthreads();   // protect rS against previous iteration's readers
    #pragma unroll
    for (int c = 0; c < 2; c++)
      #pragma unroll
      for (int r = 0; r < 4; r++) {
        float vv = eluf(acc1[c][r] + br[c * 16 + m]);
        rS[(wid * 16 + q * 4 + r) * 40 + c * 16 + m] = (_Float16)vv;
      }
    __syncthreads();

    half8_t a2 = *(const half8_t*)(&rS[(wid * 16 + m) * 40 + q * 8]);
    f32x4_t acc2[4];
    #pragma unroll
    for (int c = 0; c < 4; c++) acc2[c] = (f32x4_t){0.f, 0.f, 0.f, 0.f};
    #pragma unroll
    for (int c = 0; c < 4; c++)
      acc2[c] = __builtin_amdgcn_mfma_f32_16x16x32_f16(a2, Bwf1[c * 64 + l], acc2[c], 0, 0, 0);

    float wv[4] = {Wf2[m], Wf2[16 + m], Wf2[32 + m], Wf2[48 + m]};
    float rsum[4];
    #pragma unroll
    for (int r = 0; r < 4; r++) {
      float sr = 0.f;
      #pragma unroll
      for (int c = 0; c < 4; c++)
        sr += eluf(acc2[c][r] + bf1[c * 16 + m]) * wv[c];
      #pragma unroll
      for (int off = 1; off < 16; off <<= 1) sr += __shfl_xor(sr, off);
      rsum[r] = sr;
    }
    if (m == 0) {
      float b = bf2[0];
      #pragma unroll
      for (int r = 0; r < 4; r++) {
        int row = row0 + wid * 16 + q * 4 + r;
        if (row < NN) out[row] = rsum[r] + b;
      }
    }
  }
}

// ---------------- mega kernel (cooperative) ----------------

struct MegaParams {
  const float* x; const int* edge_src; const int* edge_dst;
  const float *W1, *as1, *ad1, *b1;
  const float *W2, *as2, *ad2, *b2;
  const float *W3, *as3, *ad3, *b3;
  const float *W4, *as4, *ad4, *b4;
  const float *Wr, *br, *Wf1, *bf1, *Wf2, *bf2;
  float* out;
  int* count; int* csr_src;
  __half *bufA, *bufB;
  float *as_b, *ad_b;
  __half *Wp1, *Wp2, *Wp3, *Wp4, *Wrp, *Wf1p;
};

__global__ __launch_bounds__(256, 5) void mega_kernel(MegaParams P) {
  cg::grid_group grid = cg::this_grid();
  __shared__ __align__(16) char smem[7680];
  float4 (*see4)[CAP] = (float4 (*)[CAP])smem;
  int    (*ssrc)[CAP] = (int (*)[CAP])(smem + 6144);
  _Float16* Ah = (_Float16*)smem;     // gemm / mlp scratch (5 KB), phase-disjoint

  zero_phase(P.count);
  grid.sync();
  scatter_pack_phase(P.edge_src, P.edge_dst, P.count, P.csr_src,
                     P.W1, P.Wp1, P.W2, P.Wp2, P.W3, P.Wp3, P.W4, P.Wp4,
                     P.Wr, P.Wrp, P.Wf1, P.Wf1p);
  grid.sync();
  gemm_phase<32, 128, 8, true>(P.x, P.Wp1, P.bufA, P.as1, P.ad1, P.as_b, P.ad_b, Ah);
  grid.sync();
  agg_phase<32, 8>(P.bufA, P.as_b, P.ad_b, P.count, P.csr_src, P.b1, P.bufB, see4, ssrc);
  grid.sync();
  gemm_phase<64, 32, 16, false>(P.bufB, P.Wp2, P.bufA, P.as2, P.ad2, P.as_b, P.ad_b, Ah);
  grid.sync();
  agg_phase<64, 16>(P.bufA, P.as_b, P.ad_b, P.count, P.csr_src, P.b2, P.bufB, see4, ssrc);
  grid.sync();
  gemm_phase<128, 64, 32, false>(P.bufB, P.Wp3, P.bufA, P.as3, P.ad3, P.as_b, P.ad_b, Ah);
  grid.sync();
  agg_phase<128, 32>(P.bufA, P.as_b, P.ad_b, P.count, P.csr_src, P.b3, P.bufB, see4, ssrc);
  grid.sync();
  gemm_phase<256, 128, 64, false>(P.bufB, P.Wp4, P.bufA, P.as4, P.ad4, P.as_b, P.ad_b, Ah);
  grid.sync();
  agg_phase<256, 64>(P.bufA, P.as_b, P.ad_b, P.count, P.csr_src, P.b4, P.bufB, see4, ssrc);
  grid.sync();
  mlp_phase(P.bufB, P.Wrp, P.br, P.Wf1p, P.bf1, P.Wf2, P.bf2, P.out, Ah);
}

// ---------------- fallback wrappers (plain launches, same phase code) -------

__global__ __launch_bounds__(256) void zero_wrap(MegaParams P) { zero_phase(P.count); }
__global__ __launch_bounds__(256) void scat_wrap(MegaParams P) {
  scatter_pack_phase(P.edge_src, P.edge_dst, P.count, P.csr_src,
                     P.W1, P.Wp1, P.W2, P.Wp2, P.W3, P.Wp3, P.W4, P.Wp4,
                     P.Wr, P.Wrp, P.Wf1, P.Wf1p);
}
template<int M, int K, int C, bool F32A>
__global__ __launch_bounds__(256) void gemm_wrap(MegaParams P, const void* A, __half* Ch,
    const float* a_src, const float* a_dst) {
  __shared__ __align__(16) _Float16 Ah[64 * 40];
  gemm_phase<M, K, C, F32A>(A, (M == 32) ? P.Wp1 : (M == 64) ? P.Wp2 : (M == 128) ? P.Wp3 : P.Wp4,
                            Ch, a_src, a_dst, P.as_b, P.ad_b, Ah);
}
template<int HC, int C>
__global__ __launch_bounds__(256) void agg_wrap(MegaParams P, const __half* h,
    const float* bias, __half* out) {
  __shared__ __align__(16) char sm[7680];
  agg_phase<HC, C>(h, P.as_b, P.ad_b, P.count, P.csr_src, bias, out,
                   (float4 (*)[CAP])sm, (int (*)[CAP])(sm + 6144));
}
__global__ __launch_bounds__(256) void mlp_wrap(MegaParams P) {
  __shared__ __align__(16) _Float16 rS[64 * 40];
  mlp_phase(P.bufB, P.Wrp, P.br, P.Wf1p, P.bf1, P.Wf2, P.bf2, P.out, rS);
}

// ---------------- launcher ----------------

extern "C" void kernel_launch(void* const* d_in, const int* in_sizes, int n_in,
                              void* d_out, int out_size, void* d_ws, size_t ws_size,
                              hipStream_t stream) {
  const float* x   = (const float*)d_in[0];
  const int*   ei  = (const int*)d_in[1];
  MegaParams P;
  P.x = x;
  P.edge_src = ei;
  P.edge_dst = ei + NE;
  P.W1 = (const float*)d_in[3];  P.as1 = (const float*)d_in[4];
  P.ad1 = (const float*)d_in[5]; P.b1 = (const float*)d_in[6];
  P.W2 = (const float*)d_in[7];  P.as2 = (const float*)d_in[8];
  P.ad2 = (const float*)d_in[9]; P.b2 = (const float*)d_in[10];
  P.W3 = (const float*)d_in[11]; P.as3 = (const float*)d_in[12];
  P.ad3 = (const float*)d_in[13]; P.b3 = (const float*)d_in[14];
  P.W4 = (const float*)d_in[15]; P.as4 = (const float*)d_in[16];
  P.ad4 = (const float*)d_in[17]; P.b4 = (const float*)d_in[18];
  P.Wr = (const float*)d_in[19]; P.br = (const float*)d_in[20];
  P.Wf1 = (const float*)d_in[21]; P.bf1 = (const float*)d_in[22];
  P.Wf2 = (const float*)d_in[23]; P.bf2 = (const float*)d_in[24];
  P.out = (float*)d_out;

  char* p = (char*)d_ws;
  auto alloc = [&](size_t bytes) {
    char* q = p;
    p += (bytes + 255) & ~(size_t)255;
    return q;
  };
  P.count   = (int*)alloc((size_t)NN * 4);
  P.csr_src = (int*)alloc((size_t)NN * CAP * 4);
  P.bufA = (__half*)alloc((size_t)NN * 256 * 2);
  P.bufB = (__half*)alloc((size_t)NN * 256 * 2);
  P.as_b = (float*)alloc((size_t)NN * 4 * 4);
  P.ad_b = (float*)alloc((size_t)NN * 4 * 4);
  P.Wp1 = (__half*)alloc((size_t)128 * 32 * 2);
  P.Wp2 = (__half*)alloc((size_t)32 * 64 * 2);
  P.Wp3 = (__half*)alloc((size_t)64 * 128 * 2);
  P.Wp4 = (__half*)alloc((size_t)128 * 256 * 2);
  P.Wrp = (__half*)alloc((size_t)256 * 32 * 2);
  P.Wf1p = (__half*)alloc((size_t)32 * 64 * 2);

  int occ = 0;
  hipError_t qe = hipOccupancyMaxActiveBlocksPerMultiprocessor(
      &occ, reinterpret_cast<const void*>(mega_kernel), 256, 0);
  if (qe != hipSuccess || occ < 1) occ = 4;
  if (occ > 8) occ = 8;
  int grid = occ * 256;   // 256 CUs on MI355X; co-residency guaranteed by query

  void* kargs[] = { (void*)&P };
  hipError_t le = hipLaunchCooperativeKernel(
      reinterpret_cast<const void*>(mega_kernel), dim3(grid), dim3(256),
      kargs, 0, stream);

  if (le != hipSuccess) {
    // fallback: same phases as plain kernels (R9-equivalent structure)
    int scg = (NEP + PACK_TOTAL + 255) / 256;
    zero_wrap<<<(NN + 255) / 256, 256, 0, stream>>>(P);
    scat_wrap<<<scg, 256, 0, stream>>>(P);
    gemm_wrap<32, 128, 8, true><<<NT, 256, 0, stream>>>(P, P.x, P.bufA, P.as1, P.ad1);
    agg_wrap<32, 8><<<NQ, 256, 0, stream>>>(P, P.bufA, P.b1, P.bufB);
    gemm_wrap<64, 32, 16, false><<<NT, 256, 0, stream>>>(P, P.bufB, P.bufA, P.as2, P.ad2);
    agg_wrap<64, 16><<<NQ, 256, 0, stream>>>(P, P.bufA, P.b2, P.bufB);
    gemm_wrap<128, 64, 32, false><<<NT, 256, 0, stream>>>(P, P.bufB, P.bufA, P.as3, P.ad3);
    agg_wrap<128, 32><<<NQ, 256, 0, stream>>>(P, P.bufA, P.b3, P.bufB);
    gemm_wrap<256, 128, 64, false><<<NT, 256, 0, stream>>>(P, P.bufB, P.bufA, P.as4, P.ad4);
    agg_wrap<256, 64><<<NQ, 256, 0, stream>>>(P, P.bufA, P.b4, P.bufB);
    mlp_wrap<<<NT, 256, 0, stream>>>(P);
  }
}

// Round 12
// 398.869 us; speedup vs baseline: 3.1363x; 3.1363x over previous
//
#include <hip/hip_runtime.h>
#include <hip/hip_fp16.h>
#include <math.h>

constexpr int NN = 50000;
constexpr int NE = 800000;
constexpr int NEP = NE + NN;             // edges + self-loops
constexpr int CAP = 96;                  // bucket capacity (Poisson(17) max ~50)
constexpr int SCAT_B = (NEP + 255) / 256;      // 3321
constexpr int PACK_B = 26;                     // 6656 pack threads (W2..Wf1)
constexpr int NT = (NN + 63) / 64;             // 782 gemm tiles

typedef _Float16 half8_t __attribute__((ext_vector_type(8)));
typedef float    f32x4_t __attribute__((ext_vector_type(4)));

__device__ __forceinline__ float lrelu02(float x) { return x > 0.f ? x : 0.2f * x; }
__device__ __forceinline__ float eluf(float x)    { return x > 0.f ? x : (__expf(x) - 1.f); }
__device__ __forceinline__ float pick4(float4 q, int hd) {
  return (hd == 0) ? q.x : (hd == 1) ? q.y : (hd == 2) ? q.z : q.w;
}

// ---------------- W pre-pack into MFMA B-fragment order ----------------

__device__ __forceinline__ void pack_w_one(const float* __restrict__ W,
                                           __half* __restrict__ Wp,
                                           int M, int tid, int total) {
  if (tid >= total) return;
  int CT = M >> 4;
  int l = tid & 63;
  int c = (tid >> 6) % CT;
  int kc = (tid >> 6) / CT;
  int n = l & 15, q = l >> 4;
  __half* dst = Wp + (size_t)tid * 8;
  const float* src = W + (size_t)(kc * 32 + q * 8) * M + c * 16 + n;
  #pragma unroll
  for (int j = 0; j < 8; j++) dst[j] = __float2half_rn(src[j * M]);
}

// ---------------- fused alpha epilogue ----------

template<int M, int C, int CT>
__device__ __forceinline__ void alpha_epilogue(const f32x4_t* acc,
    const float* __restrict__ a_src, const float* __restrict__ a_dst,
    int row_base, int m, float* __restrict__ as_out, float* __restrict__ ad_out) {
  float aS[CT], aD[CT];
  #pragma unroll
  for (int c = 0; c < CT; c++) { aS[c] = a_src[c * 16 + m]; aD[c] = a_dst[c * 16 + m]; }

  if constexpr (C == 8) {
    #pragma unroll
    for (int r = 0; r < 4; r++) {
      float p0 = acc[0][r] * aS[0], p1 = acc[1][r] * aS[1];
      float q0 = acc[0][r] * aD[0], q1 = acc[1][r] * aD[1];
      #pragma unroll
      for (int off = 1; off < 8; off <<= 1) {
        p0 += __shfl_xor(p0, off); p1 += __shfl_xor(p1, off);
        q0 += __shfl_xor(q0, off); q1 += __shfl_xor(q1, off);
      }
      int row = row_base + r;
      if ((m & 7) == 0 && row < NN) {
        int hb = m >> 3;
        as_out[row * 4 + hb]     = p0;
        as_out[row * 4 + 2 + hb] = p1;
        ad_out[row * 4 + hb]     = q0;
        ad_out[row * 4 + 2 + hb] = q1;
      }
    }
  } else {
    constexpr int FPH = C / 16;
    #pragma unroll
    for (int r = 0; r < 4; r++) {
      float bs[4] = {0.f, 0.f, 0.f, 0.f}, bd[4] = {0.f, 0.f, 0.f, 0.f};
      #pragma unroll
      for (int c = 0; c < CT; c++) {
        int hd = c / FPH;
        bs[hd] += acc[c][r] * aS[c];
        bd[hd] += acc[c][r] * aD[c];
      }
      #pragma unroll
      for (int off = 1; off < 16; off <<= 1)
        #pragma unroll
        for (int h = 0; h < 4; h++) {
          bs[h] += __shfl_xor(bs[h], off);
          bd[h] += __shfl_xor(bd[h], off);
        }
      int row = row_base + r;
      if (m < 4 && row < NN) {
        float vs = (m == 0) ? bs[0] : (m == 1) ? bs[1] : (m == 2) ? bs[2] : bs[3];
        float vd = (m == 0) ? bd[0] : (m == 1) ? bd[1] : (m == 2) ? bd[2] : bd[3];
        as_out[row * 4 + m] = vs;
        ad_out[row * 4 + m] = vd;
      }
    }
  }
}

// ---------------- merged front kernel: scatter | pack(W2..Wf1) | gemm1 ------
// Block ranges are independent workloads; gemm1 packs W1 into its own LDS
// (no dependency on the pack blocks).

__global__ __launch_bounds__(256) void front_kernel(
    const int* __restrict__ edge_src, const int* __restrict__ edge_dst,
    int* __restrict__ count, int* __restrict__ csr_src,
    const float* __restrict__ W1,
    const float* __restrict__ W2, __half* __restrict__ Wp2,
    const float* __restrict__ W3, __half* __restrict__ Wp3,
    const float* __restrict__ W4, __half* __restrict__ Wp4,
    const float* __restrict__ Wr, __half* __restrict__ Wrp,
    const float* __restrict__ Wf1, __half* __restrict__ Wf1p,
    const float* __restrict__ x, __half* __restrict__ Ch,
    const float* __restrict__ a_src, const float* __restrict__ a_dst,
    float* __restrict__ as_out, float* __restrict__ ad_out) {
  int b = blockIdx.x;
  if (b < SCAT_B) {
    int i = b * 256 + threadIdx.x;
    if (i < NEP) {
      int s, d;
      if (i < NE) { s = edge_src[i]; d = edge_dst[i]; } else { s = i - NE; d = s; }
      int pos = atomicAdd(&count[d], 1);
      if (pos < CAP) csr_src[d * CAP + pos] = s;
    }
    return;
  }
  if (b < SCAT_B + PACK_B) {
    int tid = (b - SCAT_B) * 256 + threadIdx.x;
    if (tid < 256)            pack_w_one(W2, Wp2, 64,  tid,        256);
    else if (tid < 1280)      pack_w_one(W3, Wp3, 128, tid - 256,  1024);
    else if (tid < 5376)      pack_w_one(W4, Wp4, 256, tid - 1280, 4096);
    else if (tid < 6400)      pack_w_one(Wr, Wrp, 32,  tid - 5376, 1024);
    else if (tid < 6656)      pack_w_one(Wf1, Wf1p, 64, tid - 6400, 256);
    return;
  }

  // ---- gemm1: x[NN,128] @ W1[128,32] -> Ch fp16, + alpha epilogue ----
  constexpr int M = 32, K = 128, CT = 2, KC = 4;
  __shared__ _Float16 Ah[64 * 40];
  __shared__ _Float16 Bs[KC * CT * 64 * 8];   // 4096 halves = 8 KB
  int t = threadIdx.x;
  int w = t >> 6, l = t & 63;
  int m = l & 15, q = l >> 4;
  int row0 = (b - SCAT_B - PACK_B) * 64;

  // pack W1 into LDS B-fragment layout (each thread: 2 frag-lane units)
  #pragma unroll
  for (int u0 = 0; u0 < 2; u0++) {
    int u = t + u0 * 256;            // 512 units total
    int ul = u & 63;
    int uc = (u >> 6) & 1;
    int ukc = u >> 7;
    int un = ul & 15, uq = ul >> 4;
    const float* src = W1 + (size_t)(ukc * 32 + uq * 8) * M + uc * 16 + un;
    _Float16* dst = &Bs[u * 8];
    #pragma unroll
    for (int j = 0; j < 8; j++) dst[j] = (_Float16)src[j * M];
  }

  f32x4_t acc[CT];
  #pragma unroll
  for (int c = 0; c < CT; c++) acc[c] = (f32x4_t){0.f, 0.f, 0.f, 0.f};

  for (int kc = 0; kc < KC; kc++) {
    __syncthreads();
    #pragma unroll
    for (int i = 0; i < 2; i++) {
      int idx = t + 256 * i;
      int row = idx >> 3, c4 = idx & 7;
      int gr = row0 + row; if (gr >= NN) gr = NN - 1;
      float4 v = *(const float4*)(x + (size_t)gr * K + kc * 32 + c4 * 4);
      _Float16 h4[4] = {(_Float16)v.x, (_Float16)v.y, (_Float16)v.z, (_Float16)v.w};
      *(uint2*)(&Ah[row * 40 + c4 * 4]) = *(const uint2*)h4;
    }
    __syncthreads();
    half8_t a = *(const half8_t*)(&Ah[(w * 16 + m) * 40 + q * 8]);
    #pragma unroll
    for (int c = 0; c < CT; c++) {
      half8_t bf = *(const half8_t*)(&Bs[((kc * CT + c) * 64 + l) * 8]);
      acc[c] = __builtin_amdgcn_mfma_f32_16x16x32_f16(a, bf, acc[c], 0, 0, 0);
    }
  }

  #pragma unroll
  for (int r = 0; r < 4; r++) {
    int row = row0 + w * 16 + q * 4 + r;
    if (row < NN) {
      #pragma unroll
      for (int c = 0; c < CT; c++)
        Ch[(size_t)row * M + c * 16 + m] = __float2half_rn(acc[c][r]);
    }
  }
  alpha_epilogue<M, 8, CT>(acc, a_src, a_dst, row0 + w * 16 + q * 4, m, as_out, ad_out);
}

// ---------------- MFMA GEMM (fp16 A) + fused alpha ----------

template<int M, int K, int C>
__global__ __launch_bounds__(256) void gemm_mfma_f16_kernel(const __half* __restrict__ A,
    const __half* __restrict__ Wp, __half* __restrict__ Ch,
    const float* __restrict__ a_src, const float* __restrict__ a_dst,
    float* __restrict__ as_out, float* __restrict__ ad_out) {
  constexpr int CT = M / 16;
  constexpr int KC = K / 32;
  __shared__ _Float16 Ah[64 * 40];
  int t = threadIdx.x;
  int w = t >> 6, l = t & 63;
  int m = l & 15, q = l >> 4;
  int row0 = blockIdx.x * 64;

  f32x4_t acc[CT];
  #pragma unroll
  for (int c = 0; c < CT; c++) acc[c] = (f32x4_t){0.f, 0.f, 0.f, 0.f};

  const half8_t* Bfrag = (const half8_t*)Wp;

  for (int kc = 0; kc < KC; kc++) {
    __syncthreads();
    {
      int row = t >> 2, c8 = t & 3;
      int gr = row0 + row; if (gr >= NN) gr = NN - 1;
      uint4 v = *(const uint4*)(A + (size_t)gr * K + kc * 32 + c8 * 8);
      *(uint4*)(&Ah[row * 40 + c8 * 8]) = v;
    }
    __syncthreads();
    half8_t a = *(const half8_t*)(&Ah[(w * 16 + m) * 40 + q * 8]);
    #pragma unroll
    for (int c = 0; c < CT; c++) {
      half8_t b = Bfrag[(kc * CT + c) * 64 + l];
      acc[c] = __builtin_amdgcn_mfma_f32_16x16x32_f16(a, b, acc[c], 0, 0, 0);
    }
  }

  #pragma unroll
  for (int r = 0; r < 4; r++) {
    int row = row0 + w * 16 + q * 4 + r;
    if (row < NN) {
      #pragma unroll
      for (int c = 0; c < CT; c++)
        Ch[(size_t)row * M + c * 16 + m] = __float2half_rn(acc[c][r]);
    }
  }
  alpha_epilogue<M, C, CT>(acc, a_src, a_dst, row0 + w * 16 + q * 4, m, as_out, ad_out);
}

// ---------------- aggregation: one wave per dst node (bucket CSR) ----------

template<int HC, int C>
__global__ __launch_bounds__(256) void agg_kernel(const __half* __restrict__ h,
    const float* __restrict__ as_v, const float* __restrict__ ad_v,
    const int* __restrict__ count, const int* __restrict__ csr_src,
    const float* __restrict__ bias, __half* __restrict__ out) {
  constexpr int V = HC / 8;
  constexpr int G = 64 / V;
  constexpr int P = 4;
  __shared__ float4 see4[4][CAP];
  __shared__ int    ssrc[4][CAP];
  int wid = threadIdx.x >> 6, lane = threadIdx.x & 63;
  int dst = blockIdx.x * 4 + wid;          // grid is exactly NN/4
  int base = dst * CAP;
  int deg = count[dst]; if (deg > CAP) deg = CAP;   // >= 1 (self-loop)
  float4 ad = *(const float4*)(ad_v + dst * 4);

  float d0 = 0.f, d1 = 0.f, d2 = 0.f, d3 = 0.f;
  #pragma unroll
  for (int it = 0; it < 2; it++) {
    int j = lane + it * 64;
    if (j < deg) {
      int s = csr_src[base + j];
      float4 as = *(const float4*)(as_v + s * 4);
      float4 x = make_float4(__expf(lrelu02(as.x + ad.x)), __expf(lrelu02(as.y + ad.y)),
                             __expf(lrelu02(as.z + ad.z)), __expf(lrelu02(as.w + ad.w)));
      ssrc[wid][j] = s; see4[wid][j] = x;
      d0 += x.x; d1 += x.y; d2 += x.z; d3 += x.w;
    }
  }
  #pragma unroll
  for (int off = 32; off > 0; off >>= 1) {
    d0 += __shfl_xor(d0, off); d1 += __shfl_xor(d1, off);
    d2 += __shfl_xor(d2, off); d3 += __shfl_xor(d3, off);
  }
  float4 inv = make_float4(1.f / d0, 1.f / d1, 1.f / d2, 1.f / d3);

  int g = lane / V, v = lane % V;
  int hd = (v * 8) / C;
  float invh = pick4(inv, hd);
  int steps = (deg + G - 1) / G;
  const float4* hrows = (const float4*)h;

  float  px[P];
  float4 hv[P];
  #pragma unroll
  for (int k = 0; k < P; k++) {
    int jj = k * G + g;
    bool ok = jj < deg;
    int jc = ok ? jj : 0;
    int s = ssrc[wid][jc];
    float x = ((const float*)&see4[wid][jc])[hd];
    px[k] = ok ? x * invh : 0.f;
    hv[k] = hrows[(size_t)s * V + v];
  }

  float acc[8];
  #pragma unroll
  for (int i = 0; i < 8; i++) acc[i] = 0.f;
  int nB = (steps + P - 1) / P;            // >= 1
  for (int b = 1; b <= nB; b++) {
    #pragma unroll
    for (int k = 0; k < P; k++) {
      const __half2* hp = (const __half2*)&hv[k];
      float2 f0 = __half22float2(hp[0]);
      float2 f1 = __half22float2(hp[1]);
      float2 f2 = __half22float2(hp[2]);
      float2 f3 = __half22float2(hp[3]);
      float p = px[k];
      acc[0] += p * f0.x; acc[1] += p * f0.y;
      acc[2] += p * f1.x; acc[3] += p * f1.y;
      acc[4] += p * f2.x; acc[5] += p * f2.y;
      acc[6] += p * f3.x; acc[7] += p * f3.y;
      int jj = (b * P + k) * G + g;
      bool ok = jj < deg;
      int jc = ok ? jj : 0;
      int s = ssrc[wid][jc];
      float x = ((const float*)&see4[wid][jc])[hd];
      px[k] = ok ? x * invh : 0.f;
      hv[k] = hrows[(size_t)s * V + v];
    }
  }

  #pragma unroll
  for (int off = V; off < 64; off <<= 1)
    #pragma unroll
    for (int i = 0; i < 8; i++) acc[i] += __shfl_xor(acc[i], off);

  if (lane < V) {
    const float4* b4 = (const float4*)bias;
    float4 ba = b4[2 * v], bb = b4[2 * v + 1];
    _Float16 o[8];
    o[0] = (_Float16)eluf(acc[0] + ba.x); o[1] = (_Float16)eluf(acc[1] + ba.y);
    o[2] = (_Float16)eluf(acc[2] + ba.z); o[3] = (_Float16)eluf(acc[3] + ba.w);
    o[4] = (_Float16)eluf(acc[4] + bb.x); o[5] = (_Float16)eluf(acc[5] + bb.y);
    o[6] = (_Float16)eluf(acc[6] + bb.z); o[7] = (_Float16)eluf(acc[7] + bb.w);
    *(uint4*)(out + (size_t)dst * HC + v * 8) = *(const uint4*)o;
  }
}

// ---------------- MFMA MLP head: 256 -> 32 -> 64 -> 1 ----------------

__global__ __launch_bounds__(256) void mlp_mfma_kernel(const __half* __restrict__ h4,
    const __half* __restrict__ Wrp, const float* __restrict__ br,
    const __half* __restrict__ Wf1p, const float* __restrict__ bf1,
    const float* __restrict__ Wf2, const float* __restrict__ bf2,
    float* __restrict__ out) {
  __shared__ _Float16 rS[64 * 40];
  int t = threadIdx.x;
  int w = t >> 6, l = t & 63;
  int m = l & 15, q = l >> 4;
  int row0 = blockIdx.x * 64;
  const half8_t* Bwr  = (const half8_t*)Wrp;
  const half8_t* Bwf1 = (const half8_t*)Wf1p;

  int arow = row0 + w * 16 + m; if (arow >= NN) arow = NN - 1;
  const half8_t* Arow = (const half8_t*)(h4 + (size_t)arow * 256);
  half8_t afr[8];
  #pragma unroll
  for (int kc = 0; kc < 8; kc++) afr[kc] = Arow[kc * 4 + q];
  f32x4_t acc1[2];
  acc1[0] = (f32x4_t){0.f, 0.f, 0.f, 0.f};
  acc1[1] = (f32x4_t){0.f, 0.f, 0.f, 0.f};
  #pragma unroll
  for (int kc = 0; kc < 8; kc++) {
    acc1[0] = __builtin_amdgcn_mfma_f32_16x16x32_f16(afr[kc], Bwr[(kc * 2 + 0) * 64 + l], acc1[0], 0, 0, 0);
    acc1[1] = __builtin_amdgcn_mfma_f32_16x16x32_f16(afr[kc], Bwr[(kc * 2 + 1) * 64 + l], acc1[1], 0, 0, 0);
  }
  #pragma unroll
  for (int c = 0; c < 2; c++)
    #pragma unroll
    for (int r = 0; r < 4; r++) {
      float vv = eluf(acc1[c][r] + br[c * 16 + m]);
      rS[(w * 16 + q * 4 + r) * 40 + c * 16 + m] = (_Float16)vv;
    }
  __syncthreads();

  half8_t a2 = *(const half8_t*)(&rS[(w * 16 + m) * 40 + q * 8]);
  f32x4_t acc2[4];
  #pragma unroll
  for (int c = 0; c < 4; c++) acc2[c] = (f32x4_t){0.f, 0.f, 0.f, 0.f};
  #pragma unroll
  for (int c = 0; c < 4; c++)
    acc2[c] = __builtin_amdgcn_mfma_f32_16x16x32_f16(a2, Bwf1[c * 64 + l], acc2[c], 0, 0, 0);

  float wv[4] = {Wf2[m], Wf2[16 + m], Wf2[32 + m], Wf2[48 + m]};
  float rsum[4];
  #pragma unroll
  for (int r = 0; r < 4; r++) {
    float sr = 0.f;
    #pragma unroll
    for (int c = 0; c < 4; c++)
      sr += eluf(acc2[c][r] + bf1[c * 16 + m]) * wv[c];
    #pragma unroll
    for (int off = 1; off < 16; off <<= 1) sr += __shfl_xor(sr, off);
    rsum[r] = sr;
  }
  if (m == 0) {
    float b = bf2[0];
    #pragma unroll
    for (int r = 0; r < 4; r++) {
      int row = row0 + w * 16 + q * 4 + r;
      if (row < NN) out[row] = rsum[r] + b;
    }
  }
}

// ---------------- launcher ----------------

extern "C" void kernel_launch(void* const* d_in, const int* in_sizes, int n_in,
                              void* d_out, int out_size, void* d_ws, size_t ws_size,
                              hipStream_t stream) {
  const float* x   = (const float*)d_in[0];
  const int*   ei  = (const int*)d_in[1];
  const float* W1  = (const float*)d_in[3];
  const float* as1 = (const float*)d_in[4];
  const float* ad1 = (const float*)d_in[5];
  const float* b1  = (const float*)d_in[6];
  const float* W2  = (const float*)d_in[7];
  const float* as2 = (const float*)d_in[8];
  const float* ad2 = (const float*)d_in[9];
  const float* b2  = (const float*)d_in[10];
  const float* W3  = (const float*)d_in[11];
  const float* as3 = (const float*)d_in[12];
  const float* ad3 = (const float*)d_in[13];
  const float* b3  = (const float*)d_in[14];
  const float* W4  = (const float*)d_in[15];
  const float* as4 = (const float*)d_in[16];
  const float* ad4 = (const float*)d_in[17];
  const float* b4  = (const float*)d_in[18];
  const float* Wr  = (const float*)d_in[19];
  const float* br  = (const float*)d_in[20];
  const float* Wf1 = (const float*)d_in[21];
  const float* bf1 = (const float*)d_in[22];
  const float* Wf2 = (const float*)d_in[23];
  const float* bf2 = (const float*)d_in[24];
  float* out = (float*)d_out;

  char* p = (char*)d_ws;
  auto alloc = [&](size_t bytes) {
    char* q = p;
    p += (bytes + 255) & ~(size_t)255;
    return q;
  };
  int* count   = (int*)alloc((size_t)NN * 4);
  int* csr_src = (int*)alloc((size_t)NN * CAP * 4);
  __half* Hh = (__half*)alloc((size_t)NN * 256 * 2);  // fp16 h (gather payload)
  __half* B2 = (__half*)alloc((size_t)NN * 128 * 2);  // agg out (layers 1/3)
  __half* B3 = (__half*)alloc((size_t)NN * 256 * 2);  // agg out (layers 2/4)
  float* as_buf = (float*)alloc((size_t)NN * 4 * 4);
  float* ad_buf = (float*)alloc((size_t)NN * 4 * 4);
  __half* Wp2 = (__half*)alloc((size_t)32 * 64 * 2);
  __half* Wp3 = (__half*)alloc((size_t)64 * 128 * 2);
  __half* Wp4 = (__half*)alloc((size_t)128 * 256 * 2);
  __half* Wrp = (__half*)alloc((size_t)256 * 32 * 2);
  __half* Wf1p = (__half*)alloc((size_t)32 * 64 * 2);

  const int* edge_src = ei;
  const int* edge_dst = ei + NE;

  hipMemsetAsync(count, 0, (size_t)NN * 4, stream);
  // scatter | pack | gemm1 (+alpha1) in one kernel — independent block ranges
  front_kernel<<<SCAT_B + PACK_B + NT, 256, 0, stream>>>(
      edge_src, edge_dst, count, csr_src,
      W1, W2, Wp2, W3, Wp3, W4, Wp4, Wr, Wrp, Wf1, Wf1p,
      x, Hh, as1, ad1, as_buf, ad_buf);

  int gb  = NT;
  int ggb = NN / 4;   // NN % 4 == 0

  agg_kernel<32, 8><<<ggb, 256, 0, stream>>>(Hh, as_buf, ad_buf, count, csr_src, b1, B2);

  gemm_mfma_f16_kernel<64, 32, 16><<<gb, 256, 0, stream>>>(B2, Wp2, Hh, as2, ad2, as_buf, ad_buf);
  agg_kernel<64, 16><<<ggb, 256, 0, stream>>>(Hh, as_buf, ad_buf, count, csr_src, b2, B3);

  gemm_mfma_f16_kernel<128, 64, 32><<<gb, 256, 0, stream>>>(B3, Wp3, Hh, as3, ad3, as_buf, ad_buf);
  agg_kernel<128, 32><<<ggb, 256, 0, stream>>>(Hh, as_buf, ad_buf, count, csr_src, b3, B2);

  gemm_mfma_f16_kernel<256, 128, 64><<<gb, 256, 0, stream>>>(B2, Wp4, Hh, as4, ad4, as_buf, ad_buf);
  agg_kernel<256, 64><<<ggb, 256, 0, stream>>>(Hh, as_buf, ad_buf, count, csr_src, b4, B3);

  mlp_mfma_kernel<<<gb, 256, 0, stream>>>(B3, Wrp, br, Wf1p, bf1, Wf2, bf2, out);
}